// Round 4
// baseline (947.974 us; speedup 1.0000x reference)
//
#include <hip/hip_runtime.h>

// DepthProb: out[b,k,h,w] = softmax_k( -(feat[b,0,h,w] - depint[k])^2 )
// feat (4,1,512,1024) fp32, depint (64,) fp32, out (4,64,512,1024) fp32 = 512 MiB.
//
// ROUND 4 = CALIBRATION ROUND (round-3 retry; fixed __builtin_nontemporal_store
// needing a native clang vector type, not HIP_vector_type).
// dur_us includes the harness's re-poison fills (2 GiB ws fill ~345us + out fill).
// Launch: [dp_fused x1, dp_fused_nt x4]. Round-1 measured OH + F = 538.4 us,
// this round gives OH + F + 4*F_nt, so F_nt = (dur_us - 538.4) / 4.
// ~940 => kernel ~100us (near 6.2 TB/s write ceiling, we're done).
// ~1280 => ~185us (2x headroom, attack store pattern next).
// Writes are idempotent; last launch's values validate.

#define KBINS 64
#define HW_SHIFT 19
#define HW (1 << HW_SHIFT)      // 512*1024 pixels per batch
#define NPIX (4 * HW)

typedef float f32x4 __attribute__((ext_vector_type(4)));

// ---------------- round-1 kernel, VERBATIM (reference point) --------------
__global__ __launch_bounds__(256) void dp_fused(
    const float* __restrict__ feat,
    const float* __restrict__ depint,
    float* __restrict__ out)
{
    __shared__ float sd[KBINS];
    if (threadIdx.x < KBINS) sd[threadIdx.x] = depint[threadIdx.x];
    __syncthreads();

    const int t  = blockIdx.x * 256 + threadIdx.x;
    const int p0 = t * 4;

    const float4 f4 = *reinterpret_cast<const float4*>(feat + p0);
    float f[4] = {f4.x, f4.y, f4.z, f4.w};

    float mn[4] = {1e30f, 1e30f, 1e30f, 1e30f};
    #pragma unroll
    for (int k = 0; k < KBINS; ++k) {
        const float d = sd[k];
        #pragma unroll
        for (int j = 0; j < 4; ++j) { const float df = f[j] - d; mn[j] = fminf(mn[j], df * df); }
    }
    float sum[4] = {0.f, 0.f, 0.f, 0.f};
    #pragma unroll
    for (int k = 0; k < KBINS; ++k) {
        const float d = sd[k];
        #pragma unroll
        for (int j = 0; j < 4; ++j) { const float df = f[j] - d; sum[j] += __expf(mn[j] - df * df); }
    }
    float rs[4];
    #pragma unroll
    for (int j = 0; j < 4; ++j) rs[j] = 1.0f / sum[j];

    const int b = p0 >> HW_SHIFT;
    const int q = p0 & (HW - 1);
    float* op = out + ((size_t)b << (HW_SHIFT + 6)) + q;
    #pragma unroll
    for (int k = 0; k < KBINS; ++k) {
        const float d = sd[k];
        float4 o;
        const float a0 = f[0]-d, a1 = f[1]-d, a2 = f[2]-d, a3 = f[3]-d;
        o.x = __expf(mn[0]-a0*a0)*rs[0]; o.y = __expf(mn[1]-a1*a1)*rs[1];
        o.z = __expf(mn[2]-a2*a2)*rs[2]; o.w = __expf(mn[3]-a3*a3)*rs[3];
        *reinterpret_cast<float4*>(op) = o;
        op += HW;
    }
}

// ---------------- same kernel, nontemporal native-vector stores -----------
__global__ __launch_bounds__(256) void dp_fused_nt(
    const float* __restrict__ feat,
    const float* __restrict__ depint,
    float* __restrict__ out)
{
    __shared__ float sd[KBINS];
    if (threadIdx.x < KBINS) sd[threadIdx.x] = depint[threadIdx.x];
    __syncthreads();

    const int t  = blockIdx.x * 256 + threadIdx.x;
    const int p0 = t * 4;

    const float4 f4 = *reinterpret_cast<const float4*>(feat + p0);
    float f[4] = {f4.x, f4.y, f4.z, f4.w};

    float mn[4] = {1e30f, 1e30f, 1e30f, 1e30f};
    #pragma unroll
    for (int k = 0; k < KBINS; ++k) {
        const float d = sd[k];
        #pragma unroll
        for (int j = 0; j < 4; ++j) { const float df = f[j] - d; mn[j] = fminf(mn[j], df * df); }
    }
    float sum[4] = {0.f, 0.f, 0.f, 0.f};
    #pragma unroll
    for (int k = 0; k < KBINS; ++k) {
        const float d = sd[k];
        #pragma unroll
        for (int j = 0; j < 4; ++j) { const float df = f[j] - d; sum[j] += __expf(mn[j] - df * df); }
    }
    float rs[4];
    #pragma unroll
    for (int j = 0; j < 4; ++j) rs[j] = 1.0f / sum[j];

    const int b = p0 >> HW_SHIFT;
    const int q = p0 & (HW - 1);
    float* op = out + ((size_t)b << (HW_SHIFT + 6)) + q;
    #pragma unroll
    for (int k = 0; k < KBINS; ++k) {
        const float d = sd[k];
        f32x4 o;
        const float a0 = f[0]-d, a1 = f[1]-d, a2 = f[2]-d, a3 = f[3]-d;
        o.x = __expf(mn[0]-a0*a0)*rs[0]; o.y = __expf(mn[1]-a1*a1)*rs[1];
        o.z = __expf(mn[2]-a2*a2)*rs[2]; o.w = __expf(mn[3]-a3*a3)*rs[3];
        __builtin_nontemporal_store(o, reinterpret_cast<f32x4*>(op));
        op += HW;
    }
}

extern "C" void kernel_launch(void* const* d_in, const int* in_sizes, int n_in,
                              void* d_out, int out_size, void* d_ws, size_t ws_size,
                              hipStream_t stream) {
    const float* feat   = (const float*)d_in[0];
    const float* depint = (const float*)d_in[1];
    float* out = (float*)d_out;

    const int grid = NPIX / 4 / 256;   // 2048

    // 1x reference kernel + 4x nt-store variant:
    //   F_nt = (dur_us - 538.4) / 4, overhead cancels.
    dp_fused   <<<grid, 256, 0, stream>>>(feat, depint, out);
    dp_fused_nt<<<grid, 256, 0, stream>>>(feat, depint, out);
    dp_fused_nt<<<grid, 256, 0, stream>>>(feat, depint, out);
    dp_fused_nt<<<grid, 256, 0, stream>>>(feat, depint, out);
    dp_fused_nt<<<grid, 256, 0, stream>>>(feat, depint, out);
}

// Round 6
// 539.719 us; speedup vs baseline: 1.7564x; 1.7564x over previous
//
#include <hip/hip_runtime.h>

// DepthProb: out[b,k,h,w] = softmax_k( -(feat[b,0,h,w] - depint[k])^2 )
// feat (4,1,512,1024) fp32, depint (64,) fp32, out (4,64,512,1024) fp32 = 512 MiB.
//
// ROUND 6 = ROUND 5 RESUBMIT (r5 hit GPUAcquisitionTimeout; no data).
// Calibration (r4) established: scored dur_us = ~436us harness re-poison
// overhead + kernel time. dp_fused_nt = 102.4us = 5.33 TB/s vs 6.4 TB/s the
// harness fill sustains on this allocation. This round tests the linear-run
// hypothesis UNCONFOUNDED: same total traffic (8MB read + 512MB write), but
// each block owns 4096 contiguous pixels, holds f[16] and M[16] = mn - ln(sum)
// in REGISTERS (no LDS staging of feat, no ws), and sweeps k outer, writing
// 16KiB contiguous per block per k (vs 4KiB runs before).
//   success => dur_us ~528;  null => ~538-543 => dp_fused_nt was the roofline.

#define KBINS 64
#define HW_SHIFT 19
#define HW (1 << HW_SHIFT)      // 512*1024 pixels per batch
#define NPIX (4 * HW)
#define PXB 4096                // pixels per block (divides HW)

typedef float f32x4 __attribute__((ext_vector_type(4)));

__global__ __launch_bounds__(256) void dp_sweep(
    const float* __restrict__ feat,
    const float* __restrict__ depint,
    float* __restrict__ out)
{
    __shared__ float sd[KBINS];
    if (threadIdx.x < KBINS) sd[threadIdx.x] = depint[threadIdx.x];
    __syncthreads();

    const int base = blockIdx.x * PXB;          // contiguous span, within one batch
    const int b    = base >> HW_SHIFT;
    const int q0   = base & (HW - 1);
    const int tid  = threadIdx.x;

    // ---- load 16 px/thread: 4 float4 groups at +1024-float stride --------
    float f[16];
    #pragma unroll
    for (int g = 0; g < 4; ++g) {
        const float4 v = *reinterpret_cast<const float4*>(feat + base + g * 1024 + tid * 4);
        f[4 * g + 0] = v.x; f[4 * g + 1] = v.y; f[4 * g + 2] = v.z; f[4 * g + 3] = v.w;
    }

    // ---- pass 1: mn[j] = min_k (f-d)^2 ------------------------------------
    float mn[16];
    #pragma unroll
    for (int j = 0; j < 16; ++j) mn[j] = 1e30f;
    #pragma unroll 4
    for (int k = 0; k < KBINS; ++k) {
        const float d = sd[k];
        #pragma unroll
        for (int j = 0; j < 16; ++j) {
            const float df = f[j] - d;
            mn[j] = fminf(mn[j], df * df);
        }
    }

    // ---- pass 2: sum, then fold into M = mn - ln(sum) ---------------------
    float sum[16];
    #pragma unroll
    for (int j = 0; j < 16; ++j) sum[j] = 0.f;
    #pragma unroll 4
    for (int k = 0; k < KBINS; ++k) {
        const float d = sd[k];
        #pragma unroll
        for (int j = 0; j < 16; ++j) {
            const float df = f[j] - d;
            sum[j] += __expf(mn[j] - df * df);
        }
    }
    float M[16];
    #pragma unroll
    for (int j = 0; j < 16; ++j) M[j] = mn[j] - __logf(sum[j]);

    // ---- store phase: k outer, 16 KiB contiguous per block per k ----------
    float* op = out + ((size_t)(b << 6) << HW_SHIFT) + q0 + tid * 4;
    for (int k = 0; k < KBINS; ++k) {
        const float d = sd[k];
        #pragma unroll
        for (int g = 0; g < 4; ++g) {
            f32x4 o;
            const float a0 = f[4*g+0] - d, a1 = f[4*g+1] - d,
                        a2 = f[4*g+2] - d, a3 = f[4*g+3] - d;
            o.x = __expf(M[4*g+0] - a0 * a0);
            o.y = __expf(M[4*g+1] - a1 * a1);
            o.z = __expf(M[4*g+2] - a2 * a2);
            o.w = __expf(M[4*g+3] - a3 * a3);
            __builtin_nontemporal_store(o, reinterpret_cast<f32x4*>(op + g * 1024));
        }
        op += HW;
    }
}

extern "C" void kernel_launch(void* const* d_in, const int* in_sizes, int n_in,
                              void* d_out, int out_size, void* d_ws, size_t ws_size,
                              hipStream_t stream) {
    const float* feat   = (const float*)d_in[0];
    const float* depint = (const float*)d_in[1];
    float* out = (float*)d_out;

    dp_sweep<<<NPIX / PXB, 256, 0, stream>>>(feat, depint, out);  // 512 blocks
}

// Round 7
// 526.443 us; speedup vs baseline: 1.8007x; 1.0252x over previous
//
#include <hip/hip_runtime.h>

// DepthProb: out[b,k,h,w] = softmax_k( -(feat[b,0,h,w] - depint[k])^2 )
// feat (4,1,512,1024) fp32, depint (64,) fp32 NON-INCREASING, out (4,64,512,1024).
//
// ROUND 7. r4 calibration: scored dur_us = ~436us harness re-poison + kernel.
// r6: store-pattern change was NULL (102.4 vs 103 us) -> limiter is the serial
// compute PROLOGUE (~14us aggregate VALU before any store issues) on top of the
// ~87us write-bound phase. This round shrinks the prologue ~3x:
//   pass1: 64-bin min-scan -> 6-step binary search (depint monotone) = exact mn
//   pass2: 64-exp sum -> 18-bin window around crossing (missed terms < 1.2e-4
//          relative; threshold is 2e-2)
//   exp in base-2 (v_exp_f32), fmaf single-rounding keeps dominant bin exact.
// Store phase unchanged: 64 k-slabs, nt float4 stores (proven at ceiling).
// Predict dur_us ~528-532; null (~539) => roofline, stop next round.

#define KBINS 64
#define HW_SHIFT 19
#define HW (1 << HW_SHIFT)      // 512*1024 pixels per batch
#define NPIX (4 * HW)
#define WIN 18
#define L2E 1.44269504088896f   // log2(e)
#define LN2 0.69314718055995f

typedef float f32x4 __attribute__((ext_vector_type(4)));

__global__ __launch_bounds__(256) void dp_fast(
    const float* __restrict__ feat,
    const float* __restrict__ depint,
    float* __restrict__ out)
{
    __shared__ float sd[KBINS];
    if (threadIdx.x < KBINS) sd[threadIdx.x] = depint[threadIdx.x];
    __syncthreads();

    const int t  = blockIdx.x * 256 + threadIdx.x;
    const int p0 = t * 4;

    const float4 f4 = *reinterpret_cast<const float4*>(feat + p0);
    const float f[4] = {f4.x, f4.y, f4.z, f4.w};

    // ---- pass 1a: pos[j] = #bins with d > f  (branchless binary search; ----
    //      sd is non-increasing, so the predicate "sd[n-1] > f" is monotone)
    int pos[4];
    #pragma unroll
    for (int j = 0; j < 4; ++j) {
        int p = 0;
        #pragma unroll
        for (int s = 32; s; s >>= 1) {
            const int np = p + s;               // np-1 in [0,63]
            p = (sd[np - 1] > f[j]) ? np : p;
        }
        p += (sd[p] > f[j]) ? 1 : 0;            // allow pos == 64 (all bins > f)
        pos[j] = p;
    }

    // ---- pass 1b: exact mn from the two bracketing bins --------------------
    //      d[pos-1] = smallest bin value > f, d[pos] = largest <= f.
    float mn[4];
    #pragma unroll
    for (int j = 0; j < 4; ++j) {
        const int clo = pos[j] > 0  ? pos[j] - 1 : 0;
        const int chi = pos[j] < 63 ? pos[j]     : 63;
        const float a = f[j] - sd[clo];
        const float b = f[j] - sd[chi];
        mn[j] = fminf(a * a, b * b);
    }

    // ---- pass 2: windowed normalizer, M = mn - ln(sum) ---------------------
    float M[4];
    #pragma unroll
    for (int j = 0; j < 4; ++j) {
        int klo = pos[j] - 9;
        klo = klo > 0 ? klo : 0;
        klo = klo < (KBINS - WIN) ? klo : (KBINS - WIN);
        float sum = 0.f;
        #pragma unroll
        for (int i = 0; i < WIN; ++i) {
            const float df = f[j] - sd[klo + i];
            // arg = (mn - df^2): fma single-rounding keeps small results exact
            sum += __builtin_amdgcn_exp2f(fmaf(-df, df, mn[j]) * L2E);
        }
        M[j] = fmaf(-LN2, __log2f(sum), mn[j]);   // mn - ln(sum)
    }

    // ---- pass 3: 64 k-slabs, nt float4 stores ------------------------------
    const int b = p0 >> HW_SHIFT;
    const int q = p0 & (HW - 1);
    float* op = out + ((size_t)b << (HW_SHIFT + 6)) + q;
    #pragma unroll
    for (int k = 0; k < KBINS; ++k) {
        const float d = sd[k];
        f32x4 o;
        #pragma unroll
        for (int j = 0; j < 4; ++j) {
            const float df = f[j] - d;
            o[j] = __builtin_amdgcn_exp2f(fmaf(-df, df, M[j]) * L2E);
        }
        __builtin_nontemporal_store(o, reinterpret_cast<f32x4*>(op));
        op += HW;
    }
}

extern "C" void kernel_launch(void* const* d_in, const int* in_sizes, int n_in,
                              void* d_out, int out_size, void* d_ws, size_t ws_size,
                              hipStream_t stream) {
    const float* feat   = (const float*)d_in[0];
    const float* depint = (const float*)d_in[1];
    float* out = (float*)d_out;

    dp_fast<<<NPIX / 4 / 256, 256, 0, stream>>>(feat, depint, out);  // 2048 blocks
}